// Round 8
// baseline (417.583 us; speedup 1.0000x reference)
//
#include <hip/hip_runtime.h>

#define TT 365
#define NB 16
#define NTH 1024   // 16 waves, 1 M-tile each -> 4 waves/SIMD
#define XLEN (NB * TT * 3)   // 17520 floats

typedef _Float16 halfx8 __attribute__((ext_vector_type(8)));
typedef float floatx4 __attribute__((ext_vector_type(4)));

#define MMH(A, B, C) __builtin_amdgcn_mfma_f32_16x16x32_f16((A), (B), (C), 0, 0, 0)

#define K_LO 2.44140625e-4f   // 2^-12: un-scale for the lo-weight chain

// Pre-activations arrive PRE-SCALED by -log2e (sigmoid rows) / -2log2e (g rows).
__device__ __forceinline__ float sigm2(float y) {
  return __builtin_amdgcn_rcpf(1.0f + __builtin_amdgcn_exp2f(y));
}
__device__ __forceinline__ float tanh2(float y) {
  return fmaf(2.0f, __builtin_amdgcn_rcpf(1.0f + __builtin_amdgcn_exp2f(y)), -1.0f);
}
__device__ __forceinline__ float tanhc(float c) {   // unscaled cell value
  float e = __builtin_amdgcn_exp2f(-2.8853900817779268f * c);
  return fmaf(2.0f, __builtin_amdgcn_rcpf(1.0f + e), -1.0f);
}
__device__ __forceinline__ unsigned short h16(float v) {
  _Float16 h = (_Float16)v;
  return __builtin_bit_cast(unsigned short, h);
}

// weights -> fp16 hi + fp16 (lo * 2^12); W ~= hi + K_LO * lo  (error ~2^-23)
#define LOADFRAG(SRC, SCALE, HI, LO)                                           \
  do {                                                                         \
    _Pragma("unroll")                                                          \
    for (int jj = 0; jj < 8; ++jj) {                                           \
      const float v = (SCALE) * (SRC)[jj];                                     \
      const _Float16 hh = (_Float16)v;                                         \
      (HI)[jj] = hh;                                                           \
      (LO)[jj] = (_Float16)((v - (float)hh) * 4096.0f);                        \
    }                                                                          \
  } while (0)

// L2 half-step: e = [w_ih1|w_hh1].[h1(t);h2(t-1)] ; combine2 -> h2(t) into ZW
#define E_PHASE(ZW)                                                            \
  do {                                                                         \
    floatx4 e = b1v;                                                           \
    floatx4 el = {0.f, 0.f, 0.f, 0.f};                                         \
    e  = MMH(a2h[0], bh0, e);  e  = MMH(a2h[1], bh1, e);                       \
    e  = MMH(a2h[2], bh2, e);  e  = MMH(a2h[3], bh3, e);                       \
    el = MMH(a2l[0], bh0, el); el = MMH(a2l[1], bh1, el);                      \
    el = MMH(a2l[2], bh2, el); el = MMH(a2l[3], bh3, el);                      \
    const float g0 = fmaf(K_LO, el[0], e[0]);                                  \
    const float g1 = fmaf(K_LO, el[1], e[1]);                                  \
    const float g2 = fmaf(K_LO, el[2], e[2]);                                  \
    const float g3 = fmaf(K_LO, el[3], e[3]);                                  \
    const float i2 = sigm2(g0), f2s = sigm2(g1);                               \
    const float gg = tanh2(g2), o2 = sigm2(g3);                                \
    c2 = fmaf(f2s, c2, i2 * gg);                                               \
    const float h2v = o2 * tanhc(c2);                                          \
    (ZW)[sidx2] = h16(h2v);                                                    \
  } while (0)

// L1 half-step: d = w_ih0.x(t+1) + b0 + w_hh0.h1(t) ; combine1 -> h1(t+1) into ZW
#define D_PHASE(ZW)                                                            \
  do {                                                                         \
    floatx4 d;                                                                 \
    floatx4 dl = {0.f, 0.f, 0.f, 0.f};                                         \
    d[0] = fmaf(wiX[0], xv0, fmaf(wiY[0], xv1, fmaf(wiZ[0], xv2, b0v[0])));    \
    d[1] = fmaf(wiX[1], xv0, fmaf(wiY[1], xv1, fmaf(wiZ[1], xv2, b0v[1])));    \
    d[2] = fmaf(wiX[2], xv0, fmaf(wiY[2], xv1, fmaf(wiZ[2], xv2, b0v[2])));    \
    d[3] = fmaf(wiX[3], xv0, fmaf(wiY[3], xv1, fmaf(wiZ[3], xv2, b0v[3])));    \
    d  = MMH(a1h[0], bh0, d);  d  = MMH(a1h[1], bh1, d);                       \
    dl = MMH(a1l[0], bh0, dl); dl = MMH(a1l[1], bh1, dl);                      \
    const float p0 = fmaf(K_LO, dl[0], d[0]);                                  \
    const float p1 = fmaf(K_LO, dl[1], d[1]);                                  \
    const float p2 = fmaf(K_LO, dl[2], d[2]);                                  \
    const float p3 = fmaf(K_LO, dl[3], d[3]);                                  \
    const float i1 = sigm2(p0), f1s = sigm2(p1);                               \
    const float gg = tanh2(p2), o1 = sigm2(p3);                                \
    c1 = fmaf(f1s, c1, i1 * gg);                                               \
    const float h1v = o1 * tanhc(c1);                                          \
    (ZW)[sidx1] = h16(h1v);                                                    \
  } while (0)

// One step. SIMD k hosts waves {k, k+4, k+8, k+12}; (wv>>2)&1 alternates the
// E/D order so each SIMD has 2 waves per phase order -> MFMA bursts of half
// the waves overlap combine-VALU of the other half.
#define STEP(ZR, ZW)                                                           \
  do {                                                                         \
    const halfx8* __restrict__ Z8 = (const halfx8*)(ZR);                       \
    const halfx8 bh0 = Z8[lane],       bh1 = Z8[64 + lane];                    \
    const halfx8 bh2 = Z8[128 + lane], bh3 = Z8[192 + lane];                   \
    const float xv0 = xp[0], xv1 = xp[1], xv2 = xp[2];                         \
    if (grpA) { E_PHASE(ZW); D_PHASE(ZW); }                                    \
    else      { D_PHASE(ZW); E_PHASE(ZW); }                                    \
    xp += 3;                                                                   \
    __syncthreads();                                                           \
  } while (0)

__global__ __launch_bounds__(NTH)
__attribute__((amdgpu_waves_per_eu(4, 4)))
void lstm2_mfma6(
    const float* __restrict__ x,
    const float* __restrict__ w_ih0, const float* __restrict__ w_hh0,
    const float* __restrict__ b_ih0, const float* __restrict__ b_hh0,
    const float* __restrict__ w_ih1, const float* __restrict__ w_hh1,
    const float* __restrict__ b_ih1, const float* __restrict__ b_hh1,
    float* __restrict__ out)
{
  __shared__ __align__(16) unsigned short Z[2][2048];  // fp16 h: [buf][kt][lane][8]
  __shared__ __align__(16) float xlds[XLEN];

  const int tid  = threadIdx.x;
  const int lane = tid & 63;
  const int wv   = tid >> 6;      // 0..15: one M-tile per wave
  const int n15  = lane & 15;
  const int quad = lane >> 4;
  const int bbase = blockIdx.x * NB;
  const bool grpA = ((wv >> 2) & 1) == 0;

  const float SS = -1.4426950408889634f;   // sigmoid rows
  const float SG = -2.8853900817779268f;   // g (tanh) rows
  const float sA = ((n15 & 3) == 2) ? SG : SS;

  halfx8 a1h[2], a1l[2];   // [kt]  L1 (K=64)
  halfx8 a2h[4], a2l[4];   // [kt]  L2 (K=128: [w_ih1|w_hh1])
  floatx4 wiX, wiY, wiZ, b0v, b1v;

  {
    const int mt   = wv;
    const int arow = (n15 & 3) * 64 + mt * 4 + (n15 >> 2);   // row-permuted A
    #pragma unroll
    for (int kt = 0; kt < 2; ++kt) {
      const float* src = w_hh0 + arow * 64 + kt * 32 + quad * 8;
      LOADFRAG(src, sA, a1h[kt], a1l[kt]);
    }
    #pragma unroll
    for (int kt = 0; kt < 4; ++kt) {
      const int k0 = kt * 32 + quad * 8;
      const float* src = (k0 < 64) ? (w_ih1 + arow * 64 + k0)
                                   : (w_hh1 + arow * 64 + (k0 - 64));
      LOADFRAG(src, sA, a2h[kt], a2l[kt]);
    }
    #pragma unroll
    for (int r = 0; r < 4; ++r) {
      const int crow = r * 64 + mt * 4 + quad;
      const float sC = (r == 2) ? SG : SS;
      wiX[r] = sC * w_ih0[crow * 3 + 0];
      wiY[r] = sC * w_ih0[crow * 3 + 1];
      wiZ[r] = sC * w_ih0[crow * 3 + 2];
      b0v[r] = sC * (b_ih0[crow] + b_hh0[crow]);
      b1v[r] = sC * (b_ih1[crow] + b_hh1[crow]);
    }
  }

  const int j = wv * 4 + quad;    // this thread's hidden unit (0..63)
  const int sidx1 = (j >> 5) * 512 + ((j >> 3) & 3) * 128 + n15 * 8 + (j & 7);
  const int sidx2 = sidx1 + 1024;

  {
    const float* xg = x + (size_t)bbase * (TT * 3);
    for (int i = tid; i < XLEN; i += NTH) xlds[i] = xg[i];
    for (int i = tid; i < 2048; i += NTH) { Z[0][i] = 0; Z[1][i] = 0; }
  }

  float c1 = 0.f, c2 = 0.f;
  unsigned short* const Zb0 = &Z[0][0];
  unsigned short* const Zb1 = &Z[1][0];

  __syncthreads();

  // ---- prologue: h1(0) from x(0) only (h1(-1)=0, h2(-1)=0) ----
  {
    const float xv0 = xlds[n15 * 1095 + 0];
    const float xv1 = xlds[n15 * 1095 + 1];
    const float xv2 = xlds[n15 * 1095 + 2];
    const float p0 = fmaf(wiX[0], xv0, fmaf(wiY[0], xv1, fmaf(wiZ[0], xv2, b0v[0])));
    const float p2 = fmaf(wiX[2], xv0, fmaf(wiY[2], xv1, fmaf(wiZ[2], xv2, b0v[2])));
    const float p3 = fmaf(wiX[3], xv0, fmaf(wiY[3], xv1, fmaf(wiZ[3], xv2, b0v[3])));
    const float ig = sigm2(p0), gg = tanh2(p2), og = sigm2(p3);
    c1 = ig * gg;
    Zb0[sidx1] = h16(og * tanhc(c1));
  }
  __syncthreads();

  // ---- main loop: 182 step-pairs (t=0..363), then peel t=364 ----
  const float* xp = xlds + n15 * 1095 + 3;   // x(t+1), starting at t=0
  for (int it = 0; it < 182; ++it) {
    STEP(Zb0, Zb1);
    STEP(Zb1, Zb0);
  }

  // ---- peel t=364: L2 only, write output from registers ----
  {
    const halfx8* __restrict__ Z8 = (const halfx8*)Zb0;
    const halfx8 bh0 = Z8[lane],       bh1 = Z8[64 + lane];
    const halfx8 bh2 = Z8[128 + lane], bh3 = Z8[192 + lane];
    floatx4 e = b1v;
    floatx4 el = {0.f, 0.f, 0.f, 0.f};
    e  = MMH(a2h[0], bh0, e);  e  = MMH(a2h[1], bh1, e);
    e  = MMH(a2h[2], bh2, e);  e  = MMH(a2h[3], bh3, e);
    el = MMH(a2l[0], bh0, el); el = MMH(a2l[1], bh1, el);
    el = MMH(a2l[2], bh2, el); el = MMH(a2l[3], bh3, el);
    const float g0 = fmaf(K_LO, el[0], e[0]);
    const float g1 = fmaf(K_LO, el[1], e[1]);
    const float g2 = fmaf(K_LO, el[2], e[2]);
    const float g3 = fmaf(K_LO, el[3], e[3]);
    const float i2 = sigm2(g0), f2s = sigm2(g1);
    const float gg = tanh2(g2), o2 = sigm2(g3);
    c2 = fmaf(f2s, c2, i2 * gg);
    const float h2v = o2 * tanhc(c2);
    out[(size_t)(bbase + n15) * 64 + j] = h2v;
  }
}

extern "C" void kernel_launch(void* const* d_in, const int* in_sizes, int n_in,
                              void* d_out, int out_size, void* d_ws, size_t ws_size,
                              hipStream_t stream) {
  const float* x     = (const float*)d_in[0];
  const float* w_ih0 = (const float*)d_in[1];
  const float* w_hh0 = (const float*)d_in[2];
  const float* b_ih0 = (const float*)d_in[3];
  const float* b_hh0 = (const float*)d_in[4];
  const float* w_ih1 = (const float*)d_in[5];
  const float* w_hh1 = (const float*)d_in[6];
  const float* b_ih1 = (const float*)d_in[7];
  const float* b_hh1 = (const float*)d_in[8];
  float* out = (float*)d_out;

  const int B = in_sizes[0] / (TT * 3);   // 4096
  const int grid = B / NB;                // 256 blocks -> 1 per CU

  lstm2_mfma6<<<dim3(grid), dim3(NTH), 0, stream>>>(
      x, w_ih0, w_hh0, b_ih0, b_hh0, w_ih1, w_hh1, b_ih1, b_hh1, out);
}

// Round 9
// 351.692 us; speedup vs baseline: 1.1874x; 1.1874x over previous
//
#include <hip/hip_runtime.h>

#define TT 365
#define NB 16
#define NTH 1024   // 16 waves, 1 M-tile each -> 4 waves/SIMD
#define XLEN (NB * TT * 3)   // 17520 floats

typedef _Float16 halfx8 __attribute__((ext_vector_type(8)));
typedef float floatx4 __attribute__((ext_vector_type(4)));

#define MMH(A, B, C) __builtin_amdgcn_mfma_f32_16x16x32_f16((A), (B), (C), 0, 0, 0)

// Pre-activations arrive PRE-SCALED by -log2e (sigmoid rows) / -2log2e (g rows).
__device__ __forceinline__ float sigm2(float y) {
  return __builtin_amdgcn_rcpf(1.0f + __builtin_amdgcn_exp2f(y));
}
__device__ __forceinline__ float tanh2(float y) {
  return fmaf(2.0f, __builtin_amdgcn_rcpf(1.0f + __builtin_amdgcn_exp2f(y)), -1.0f);
}
__device__ __forceinline__ float tanhc(float c) {   // unscaled cell value
  float e = __builtin_amdgcn_exp2f(-2.8853900817779268f * c);
  return fmaf(2.0f, __builtin_amdgcn_rcpf(1.0f + e), -1.0f);
}
__device__ __forceinline__ unsigned short h16(float v) {
  _Float16 h = (_Float16)v;
  return __builtin_bit_cast(unsigned short, h);
}

// weights -> plain fp16 (RNE). Rel err ~2^-12 systematic; analysis in header note.
#define LOADFRAG(SRC, SCALE, HI)                                               \
  do {                                                                         \
    _Pragma("unroll")                                                          \
    for (int jj = 0; jj < 8; ++jj) {                                           \
      (HI)[jj] = (_Float16)((SCALE) * (SRC)[jj]);                              \
    }                                                                          \
  } while (0)

// L2 half-step: e = [w_ih1|w_hh1].[h1(t);h2(t-1)] + b1 ; combine2 -> h2(t)
#define E_PHASE(ZW)                                                            \
  do {                                                                         \
    floatx4 e = b1v;                                                           \
    e = MMH(a2h[0], bh0, e); e = MMH(a2h[1], bh1, e);                          \
    e = MMH(a2h[2], bh2, e); e = MMH(a2h[3], bh3, e);                          \
    const float i2 = sigm2(e[0]), f2s = sigm2(e[1]);                           \
    const float gg = tanh2(e[2]), o2 = sigm2(e[3]);                            \
    c2 = fmaf(f2s, c2, i2 * gg);                                               \
    const float h2v = o2 * tanhc(c2);                                          \
    (ZW)[sidx2] = h16(h2v);                                                    \
  } while (0)

// L1 half-step: d = w_ih0.x(t+1) + b0 + w_hh0.h1(t) ; combine1 -> h1(t+1)
#define D_PHASE(ZW)                                                            \
  do {                                                                         \
    const floatx4 s0 = {xv0, xv0, xv0, xv0};                                   \
    const floatx4 s1 = {xv1, xv1, xv1, xv1};                                   \
    const floatx4 s2 = {xv2, xv2, xv2, xv2};                                   \
    floatx4 d = __builtin_elementwise_fma(wiX, s0,                             \
                  __builtin_elementwise_fma(wiY, s1,                           \
                    __builtin_elementwise_fma(wiZ, s2, b0v)));                 \
    d = MMH(a1h[0], bh0, d); d = MMH(a1h[1], bh1, d);                          \
    const float i1 = sigm2(d[0]), f1s = sigm2(d[1]);                           \
    const float gg = tanh2(d[2]), o1 = sigm2(d[3]);                            \
    c1 = fmaf(f1s, c1, i1 * gg);                                               \
    const float h1v = o1 * tanhc(c1);                                          \
    (ZW)[sidx1] = h16(h1v);                                                    \
  } while (0)

#define STEP(ZR, ZW)                                                           \
  do {                                                                         \
    const halfx8* __restrict__ Z8 = (const halfx8*)(ZR);                       \
    const halfx8 bh0 = Z8[lane],       bh1 = Z8[64 + lane];                    \
    const halfx8 bh2 = Z8[128 + lane], bh3 = Z8[192 + lane];                   \
    const float xv0 = xp[0], xv1 = xp[1], xv2 = xp[2];                         \
    if (grpA) { E_PHASE(ZW); D_PHASE(ZW); }                                    \
    else      { D_PHASE(ZW); E_PHASE(ZW); }                                    \
    xp += 3;                                                                   \
    __syncthreads();                                                           \
  } while (0)

__global__ __launch_bounds__(NTH)
__attribute__((amdgpu_waves_per_eu(4, 4)))
void lstm2_mfma7(
    const float* __restrict__ x,
    const float* __restrict__ w_ih0, const float* __restrict__ w_hh0,
    const float* __restrict__ b_ih0, const float* __restrict__ b_hh0,
    const float* __restrict__ w_ih1, const float* __restrict__ w_hh1,
    const float* __restrict__ b_ih1, const float* __restrict__ b_hh1,
    float* __restrict__ out)
{
  __shared__ __align__(16) unsigned short Z[2][2048];  // fp16 h: [buf][kt][lane][8]
  __shared__ __align__(16) float xlds[XLEN];

  const int tid  = threadIdx.x;
  const int lane = tid & 63;
  const int wv   = tid >> 6;      // 0..15: one M-tile per wave
  const int n15  = lane & 15;
  const int quad = lane >> 4;
  const int bbase = blockIdx.x * NB;
  const bool grpA = ((wv >> 2) & 1) == 0;

  const float SS = -1.4426950408889634f;   // sigmoid rows
  const float SG = -2.8853900817779268f;   // g (tanh) rows
  const float sA = ((n15 & 3) == 2) ? SG : SS;

  halfx8 a1h[2];   // [kt]  L1 (K=64)
  halfx8 a2h[4];   // [kt]  L2 (K=128: [w_ih1|w_hh1])
  floatx4 wiX, wiY, wiZ, b0v, b1v;

  {
    const int mt   = wv;
    const int arow = (n15 & 3) * 64 + mt * 4 + (n15 >> 2);   // row-permuted A
    #pragma unroll
    for (int kt = 0; kt < 2; ++kt) {
      const float* src = w_hh0 + arow * 64 + kt * 32 + quad * 8;
      LOADFRAG(src, sA, a1h[kt]);
    }
    #pragma unroll
    for (int kt = 0; kt < 4; ++kt) {
      const int k0 = kt * 32 + quad * 8;
      const float* src = (k0 < 64) ? (w_ih1 + arow * 64 + k0)
                                   : (w_hh1 + arow * 64 + (k0 - 64));
      LOADFRAG(src, sA, a2h[kt]);
    }
    #pragma unroll
    for (int r = 0; r < 4; ++r) {
      const int crow = r * 64 + mt * 4 + quad;
      const float sC = (r == 2) ? SG : SS;
      wiX[r] = sC * w_ih0[crow * 3 + 0];
      wiY[r] = sC * w_ih0[crow * 3 + 1];
      wiZ[r] = sC * w_ih0[crow * 3 + 2];
      b0v[r] = sC * (b_ih0[crow] + b_hh0[crow]);
      b1v[r] = sC * (b_ih1[crow] + b_hh1[crow]);
    }
  }

  const int j = wv * 4 + quad;    // this thread's hidden unit (0..63)
  const int sidx1 = (j >> 5) * 512 + ((j >> 3) & 3) * 128 + n15 * 8 + (j & 7);
  const int sidx2 = sidx1 + 1024;

  {
    const float* xg = x + (size_t)bbase * (TT * 3);
    for (int i = tid; i < XLEN; i += NTH) xlds[i] = xg[i];
    for (int i = tid; i < 2048; i += NTH) { Z[0][i] = 0; Z[1][i] = 0; }
  }

  float c1 = 0.f, c2 = 0.f;
  unsigned short* const Zb0 = &Z[0][0];
  unsigned short* const Zb1 = &Z[1][0];

  __syncthreads();

  // ---- prologue: h1(0) from x(0) only (h1(-1)=0, h2(-1)=0) ----
  {
    const float xv0 = xlds[n15 * 1095 + 0];
    const float xv1 = xlds[n15 * 1095 + 1];
    const float xv2 = xlds[n15 * 1095 + 2];
    const float p0 = fmaf(wiX[0], xv0, fmaf(wiY[0], xv1, fmaf(wiZ[0], xv2, b0v[0])));
    const float p2 = fmaf(wiX[2], xv0, fmaf(wiY[2], xv1, fmaf(wiZ[2], xv2, b0v[2])));
    const float p3 = fmaf(wiX[3], xv0, fmaf(wiY[3], xv1, fmaf(wiZ[3], xv2, b0v[3])));
    const float ig = sigm2(p0), gg = tanh2(p2), og = sigm2(p3);
    c1 = ig * gg;
    Zb0[sidx1] = h16(og * tanhc(c1));
  }
  __syncthreads();

  // ---- main loop: 182 step-pairs (t=0..363), then peel t=364 ----
  const float* xp = xlds + n15 * 1095 + 3;   // x(t+1), starting at t=0
  for (int it = 0; it < 182; ++it) {
    STEP(Zb0, Zb1);
    STEP(Zb1, Zb0);
  }

  // ---- peel t=364: L2 only, write output from registers ----
  {
    const halfx8* __restrict__ Z8 = (const halfx8*)Zb0;
    const halfx8 bh0 = Z8[lane],       bh1 = Z8[64 + lane];
    const halfx8 bh2 = Z8[128 + lane], bh3 = Z8[192 + lane];
    floatx4 e = b1v;
    e = MMH(a2h[0], bh0, e); e = MMH(a2h[1], bh1, e);
    e = MMH(a2h[2], bh2, e); e = MMH(a2h[3], bh3, e);
    const float i2 = sigm2(e[0]), f2s = sigm2(e[1]);
    const float gg = tanh2(e[2]), o2 = sigm2(e[3]);
    c2 = fmaf(f2s, c2, i2 * gg);
    const float h2v = o2 * tanhc(c2);
    out[(size_t)(bbase + n15) * 64 + j] = h2v;
  }
}

extern "C" void kernel_launch(void* const* d_in, const int* in_sizes, int n_in,
                              void* d_out, int out_size, void* d_ws, size_t ws_size,
                              hipStream_t stream) {
  const float* x     = (const float*)d_in[0];
  const float* w_ih0 = (const float*)d_in[1];
  const float* w_hh0 = (const float*)d_in[2];
  const float* b_ih0 = (const float*)d_in[3];
  const float* b_hh0 = (const float*)d_in[4];
  const float* w_ih1 = (const float*)d_in[5];
  const float* w_hh1 = (const float*)d_in[6];
  const float* b_ih1 = (const float*)d_in[7];
  const float* b_hh1 = (const float*)d_in[8];
  float* out = (float*)d_out;

  const int B = in_sizes[0] / (TT * 3);   // 4096
  const int grid = B / NB;                // 256 blocks -> 1 per CU

  lstm2_mfma7<<<dim3(grid), dim3(NTH), 0, stream>>>(
      x, w_ih0, w_hh0, b_ih0, b_hh0, w_ih1, w_hh1, b_ih1, b_hh1, out);
}